// Round 15
// baseline (406.434 us; speedup 1.0000x reference)
//
#include <hip/hip_runtime.h>
#include <cfloat>
#include <cstdint>

#define NB 32
#define NP 1024
#define NK 20
#define NPTS 32768  // NB*NP

typedef __attribute__((ext_vector_type(8))) short bf16x8;
typedef __attribute__((ext_vector_type(4))) float f32x4;

__device__ __forceinline__ unsigned bf16rne(float v) {
  const unsigned u = __float_as_uint(v);
  return (u + 0x7fffu + ((u >> 16) & 1u)) >> 16;
}

// ---------------------------------------------------------------------------
// d2[p] = sum x^2 (fp32 exact; chain order matched with kdsel3 dot).
// ---------------------------------------------------------------------------
__global__ __launch_bounds__(256) void kd2(const float* __restrict__ x, int dim,
                                           float* __restrict__ d2) {
  int p = blockIdx.x * 256 + threadIdx.x;
  if (p >= NPTS) return;
  if (dim == 64) {
    const float4* xr = (const float4*)(x + (size_t)p * 64);
    float s = 0.f;
#pragma unroll
    for (int dq = 0; dq < 16; dq++) {
      float4 v = xr[dq];
      s = fmaf(v.x, v.x, s);
      s = fmaf(v.y, v.y, s);
      s = fmaf(v.z, v.z, s);
      s = fmaf(v.w, v.w, s);
    }
    d2[p] = s;
  } else {
    float s = 0.f;
#pragma unroll
    for (int d = 0; d < 3; d++) {
      float v = x[p * 3 + d];
      s = fmaf(v, v, s);
    }
    d2[p] = s;
  }
}

// ---------------------------------------------------------------------------
// kxprep: convert x1 into MFMA fragment order, bf16 hi/lo (HW-validated
// mapping, R13/R14). Same array serves A and B operands of S = X X^T.
// ---------------------------------------------------------------------------
__global__ __launch_bounds__(256) void kxprep(const float* __restrict__ x,
                                              unsigned short* __restrict__ Xh,
                                              unsigned short* __restrict__ Xl) {
  const int t = blockIdx.x * 256 + threadIdx.x;  // 262144
  const int p = t >> 3, g = t & 7;               // k = g*8 + j
  const float4* xr = (const float4*)(x + (size_t)p * 64 + g * 8);
  const float4 v0 = xr[0];
  const float4 v1 = xr[1];
  const float vv[8] = {v0.x, v0.y, v0.z, v0.w, v1.x, v1.y, v1.z, v1.w};
  unsigned short h[8], l[8];
#pragma unroll
  for (int j = 0; j < 8; j++) {
    const float z = vv[j];
    const unsigned u = __float_as_uint(z);
    const unsigned hb = (u + 0x7fffu + ((u >> 16) & 1u)) & 0xffff0000u;
    h[j] = (unsigned short)(hb >> 16);
    l[j] = (unsigned short)bf16rne(z - __uint_as_float(hb));
  }
  const int off = (((p >> 4) * 2 + (g >> 2)) * 64 + ((g & 3) << 4) + (p & 15)) * 8;
  *(uint4*)&Xh[off] = *(const uint4*)&h[0];
  *(uint4*)&Xl[off] = *(const uint4*)&l[0];
}

// ---------------------------------------------------------------------------
// wave_select_half: exact top-20 of one 512-col half-row from LDS, via the
// R4-validated pivot selection (distinct packed keys -> window [20,63]
// exists). Writes ranked keys to cand[half*20 + rank].
// ---------------------------------------------------------------------------
__device__ __forceinline__ void wave_select_half(
    const float* __restrict__ DtRow, int half, int lane,
    unsigned long long* __restrict__ lww,
    unsigned long long* __restrict__ candp) {
  unsigned long long key[8];
#pragma unroll
  for (int i = 0; i < 2; i++) {
    const float4 d4 = ((const float4*)DtRow)[i * 64 + lane];
    const float dv[4] = {d4.x, d4.y, d4.z, d4.w};
#pragma unroll
    for (int j = 0; j < 4; j++) {
      unsigned u = __float_as_uint(dv[j]);
      u ^= (((int)u >> 31) | 0x80000000u);  // sortable transform
      key[i * 4 + j] = ((unsigned long long)u << 10) |
                       (unsigned)(half * 512 + i * 256 + lane * 4 + j);
    }
  }
  unsigned long long mn = key[0], mx = key[0];
#pragma unroll
  for (int i = 1; i < 8; i++) {
    mn = key[i] < mn ? key[i] : mn;
    mx = key[i] > mx ? key[i] : mx;
  }
#pragma unroll
  for (int s = 1; s < 64; s <<= 1) {
    unsigned long long a = __shfl_xor(mn, s, 64);
    unsigned long long b = __shfl_xor(mx, s, 64);
    mn = a < mn ? a : mn;
    mx = b > mx ? b : mx;
  }
  unsigned long long lo = mn, hi = mx + 1, mid = hi;
  bool found = false;
  for (int it = 0; it < 48 && !found; ++it) {
    unsigned long long m2 = lo + ((hi - lo) >> 1);
    int cnt = 0;
#pragma unroll
    for (int i = 0; i < 8; i++) cnt += (key[i] < m2) ? 1 : 0;
#pragma unroll
    for (int s = 1; s < 64; s <<= 1) cnt += __shfl_xor(cnt, s, 64);
    if (cnt < 20)
      lo = m2;
    else if (cnt > 63)
      hi = m2;
    else {
      mid = m2;
      found = true;
    }
  }
  unsigned mask = 0;
#pragma unroll
  for (int i = 0; i < 8; i++) mask |= (key[i] < mid) ? (1u << i) : 0u;
  const int lc = __popc(mask);
  int x = lc;
#pragma unroll
  for (int s = 1; s < 64; s <<= 1) {
    int y = __shfl_up(x, s, 64);
    if (lane >= s) x += y;
  }
  int off = x - lc;                    // exclusive prefix
  const int ctot = __shfl(x, 63, 64);  // total candidates (20..63)
  const int c = ctot < 64 ? ctot : 64;
  lww[lane] = ~0ULL;  // pad for fixed-64 rank pass
  __builtin_amdgcn_wave_barrier();
#pragma unroll
  for (int i = 0; i < 8; i++) {
    if ((mask & (1u << i)) && off < 64) {
      lww[off] = key[i];
      off++;
    }
  }
  __builtin_amdgcn_wave_barrier();
  const unsigned long long K = lww[lane];
  int rank = 0;
#pragma unroll
  for (int m = 0; m < 64; m++) rank += (K > lww[m]) ? 1 : 0;
  if (lane < c && rank < NK) candp[half * NK + rank] = K;
}

// ---------------------------------------------------------------------------
// kdsel3: fused distance + exact top-20 selection for layer 1 (dim=3).
// Block = 16 points x 1024 cols, processed in 2 column-halves through LDS
// (Dt 16x516 = 33 KB; ~40 KB total -> 4 blocks/CU). No D matrix in global.
// Dot chain matches kd2 -> diagonal dist exactly 0 (bit-identical to R14).
// ---------------------------------------------------------------------------
__global__ __launch_bounds__(256) void kdsel3(const float* __restrict__ pos,
                                              const float* __restrict__ d2,
                                              int* __restrict__ idxo) {
  __shared__ float Dt[16 * 516];
  __shared__ unsigned long long cand[16 * 40];
  __shared__ unsigned long long lw[4][64];
  const int tid = threadIdx.x, lane = tid & 63, w = tid >> 6;
  const int cloud = blockIdx.x & 31, tb = blockIdx.x >> 5;
  const int cb = cloud * 1024, p0 = cb + tb * 16;

  for (int h = 0; h < 2; h++) {
    const int cl = h * 512 + w * 128 + lane * 2;  // this lane's 2 cols (cloud-local)
    const float q0x = pos[(cb + cl) * 3], q0y = pos[(cb + cl) * 3 + 1],
                q0z = pos[(cb + cl) * 3 + 2];
    const float q1x = pos[(cb + cl + 1) * 3], q1y = pos[(cb + cl + 1) * 3 + 1],
                q1z = pos[(cb + cl + 1) * 3 + 2];
    const float d2c0 = d2[cb + cl], d2c1 = d2[cb + cl + 1];
#pragma unroll
    for (int row = 0; row < 16; row++) {
      const float xi0 = pos[(p0 + row) * 3], xi1 = pos[(p0 + row) * 3 + 1],
                  xi2 = pos[(p0 + row) * 3 + 2];
      const float d2rv = d2[p0 + row];
      float s0 = 0.f, s1 = 0.f;
      s0 = fmaf(xi0, q0x, s0);
      s0 = fmaf(xi1, q0y, s0);
      s0 = fmaf(xi2, q0z, s0);
      s1 = fmaf(xi0, q1x, s1);
      s1 = fmaf(xi1, q1y, s1);
      s1 = fmaf(xi2, q1z, s1);
      float2 o;
      o.x = fmaf(-2.f, s0, d2rv + d2c0);
      o.y = fmaf(-2.f, s1, d2rv + d2c1);
      *(float2*)&Dt[row * 516 + (w * 128 + lane * 2)] = o;
    }
    __syncthreads();
    for (int s8 = 0; s8 < 4; s8++) {
      const int pl = w * 4 + s8;
      wave_select_half(&Dt[pl * 516], h, lane, lw[w], &cand[pl * 40]);
      __builtin_amdgcn_wave_barrier();
    }
    __syncthreads();
  }
  // merge 2x20 -> top-20 (exact set AND ascending order)
  for (int s8 = 0; s8 < 4; s8++) {
    const int pl = w * 4 + s8;
    const int pg = p0 + pl;
    const unsigned long long* cp = &cand[pl * 40];
    const unsigned long long K = (lane < 40) ? cp[lane] : ~0ULL;
    int rank = 0;
#pragma unroll
    for (int m = 0; m < 40; m++) rank += (K > cp[m]) ? 1 : 0;
    if (lane < 40 && rank < NK) idxo[(size_t)pg * NK + rank] = cb + (int)(K & 1023u);
  }
}

// ---------------------------------------------------------------------------
// kdsel64: fused MFMA distance + selection for layer 2 (dim=64, bf16x3
// split, same 6-product order as R14's kdistm -> bit-identical distances).
// ---------------------------------------------------------------------------
__global__ __launch_bounds__(256) void kdsel64(const unsigned short* __restrict__ Xh,
                                               const unsigned short* __restrict__ Xl,
                                               const float* __restrict__ d2,
                                               int* __restrict__ idxo) {
  __shared__ float Dt[16 * 516];
  __shared__ unsigned long long cand[16 * 40];
  __shared__ unsigned long long lw[4][64];
  const int tid = threadIdx.x, lane = tid & 63, w = tid >> 6;
  const int cloud = blockIdx.x & 31, tb = blockIdx.x >> 5;
  const int cb = cloud * 1024, p0 = cb + tb * 16;
  const int q4 = (lane >> 4) * 4, c16 = lane & 15;

  bf16x8 A_h[2], A_l[2];
  const int tgA = cloud * 64 + tb;
#pragma unroll
  for (int ks = 0; ks < 2; ks++) {
    const size_t base = ((size_t)(tgA * 2 + ks) * 64 + lane) * 8;
    A_h[ks] = *(const bf16x8*)&Xh[base];
    A_l[ks] = *(const bf16x8*)&Xl[base];
  }
  float d2r[4];
#pragma unroll
  for (int r = 0; r < 4; r++) d2r[r] = d2[p0 + q4 + r];

  for (int h = 0; h < 2; h++) {
    for (int nt = 0; nt < 8; nt++) {
      const int cl = h * 512 + w * 128 + nt * 16;  // col-tile base (cloud-local)
      const int tgB = cloud * 64 + (cl >> 4);
      bf16x8 B_h[2], B_l[2];
#pragma unroll
      for (int ks = 0; ks < 2; ks++) {
        const size_t base = ((size_t)(tgB * 2 + ks) * 64 + lane) * 8;
        B_h[ks] = *(const bf16x8*)&Xh[base];
        B_l[ks] = *(const bf16x8*)&Xl[base];
      }
      f32x4 C = {0.f, 0.f, 0.f, 0.f};
      C = __builtin_amdgcn_mfma_f32_16x16x32_bf16(A_h[0], B_h[0], C, 0, 0, 0);
      C = __builtin_amdgcn_mfma_f32_16x16x32_bf16(A_h[0], B_l[0], C, 0, 0, 0);
      C = __builtin_amdgcn_mfma_f32_16x16x32_bf16(A_l[0], B_h[0], C, 0, 0, 0);
      C = __builtin_amdgcn_mfma_f32_16x16x32_bf16(A_h[1], B_h[1], C, 0, 0, 0);
      C = __builtin_amdgcn_mfma_f32_16x16x32_bf16(A_h[1], B_l[1], C, 0, 0, 0);
      C = __builtin_amdgcn_mfma_f32_16x16x32_bf16(A_l[1], B_h[1], C, 0, 0, 0);
      const float d2c = d2[cb + cl + c16];
#pragma unroll
      for (int r = 0; r < 4; r++)
        Dt[(q4 + r) * 516 + (w * 128 + nt * 16 + c16)] =
            fmaf(-2.f, C[r], d2r[r] + d2c);
    }
    __syncthreads();
    for (int s8 = 0; s8 < 4; s8++) {
      const int pl = w * 4 + s8;
      wave_select_half(&Dt[pl * 516], h, lane, lw[w], &cand[pl * 40]);
      __builtin_amdgcn_wave_barrier();
    }
    __syncthreads();
  }
  for (int s8 = 0; s8 < 4; s8++) {
    const int pl = w * 4 + s8;
    const int pg = p0 + pl;
    const unsigned long long* cp = &cand[pl * 40];
    const unsigned long long K = (lane < 40) ? cp[lane] : ~0ULL;
    int rank = 0;
#pragma unroll
    for (int m = 0; m < 40; m++) rank += (K > cp[m]) ? 1 : 0;
    if (lane < 40 && rank < NK) idxo[(size_t)pg * NK + rank] = cb + (int)(K & 1023u);
  }
}

// ---------------------------------------------------------------------------
// Edge moments, atomic-free.
// ---------------------------------------------------------------------------
__global__ __launch_bounds__(256) void kstats(const float* __restrict__ pos,
                                              const int* __restrict__ idx,
                                              double* __restrict__ Spart) {
  __shared__ float red[4][42];
  const int tid = threadIdx.x;
  const int w = tid >> 6;
  int p = blockIdx.x * 256 + tid;
  float xi0 = pos[p * 3], xi1 = pos[p * 3 + 1], xi2 = pos[p * 3 + 2];
  float s1[6];
  float s2[36];
#pragma unroll
  for (int a = 0; a < 6; a++) s1[a] = 0.f;
#pragma unroll
  for (int a = 0; a < 36; a++) s2[a] = 0.f;
  for (int k = 0; k < NK; k++) {
    int j = idx[p * NK + k];
    float e[6];
    e[0] = xi0;
    e[1] = xi1;
    e[2] = xi2;
    e[3] = pos[j * 3] - xi0;
    e[4] = pos[j * 3 + 1] - xi1;
    e[5] = pos[j * 3 + 2] - xi2;
#pragma unroll
    for (int a = 0; a < 6; a++) {
      s1[a] += e[a];
#pragma unroll
      for (int b = 0; b < 6; b++) s2[a * 6 + b] = fmaf(e[a], e[b], s2[a * 6 + b]);
    }
  }
#pragma unroll
  for (int a = 0; a < 6; a++) {
#pragma unroll
    for (int m = 1; m < 64; m <<= 1) s1[a] += __shfl_xor(s1[a], m, 64);
  }
#pragma unroll
  for (int a = 0; a < 36; a++) {
#pragma unroll
    for (int m = 1; m < 64; m <<= 1) s2[a] += __shfl_xor(s2[a], m, 64);
  }
  if ((tid & 63) == 0) {
#pragma unroll
    for (int a = 0; a < 6; a++) red[w][a] = s1[a];
#pragma unroll
    for (int a = 0; a < 36; a++) red[w][6 + a] = s2[a];
  }
  __syncthreads();
  if (tid < 42) {
    double t = (double)red[0][tid] + (double)red[1][tid] + (double)red[2][tid] +
               (double)red[3][tid];
    Spart[(size_t)blockIdx.x * 42 + tid] = t;
  }
}

// ---------------------------------------------------------------------------
// kbn: stats reduce -> BN scale/shift; W1b pre-swizzle to B-frag bf16 hi/lo.
// ---------------------------------------------------------------------------
__global__ void kbn(const double* __restrict__ Spart, const float* __restrict__ W1a,
                    const float* __restrict__ b1a, const float* __restrict__ g1,
                    const float* __restrict__ be1, const float* __restrict__ W1b,
                    float* __restrict__ ss, unsigned short* __restrict__ Bh,
                    unsigned short* __restrict__ Bl) {
  __shared__ double S[42];
  const int c = threadIdx.x;  // 256 threads
  if (c < 42) {
    double t = 0.0;
    for (int b = 0; b < 128; b++) t += Spart[(size_t)b * 42 + c];
    S[c] = t;
  }
  for (int t = c; t < 4096; t += 256) {
    const int j = t & 7, L = (t >> 3) & 63, f = t >> 9;  // f = nt*2+ks
    const int nt = f >> 1, ks = f & 1;
    const int k = ks * 32 + (L >> 4) * 8 + j;
    const int n = nt * 16 + (L & 15);
    const float wv = W1b[k * 64 + n];
    const unsigned u = __float_as_uint(wv);
    const unsigned hb = (u + 0x7fffu + ((u >> 16) & 1u)) & 0xffff0000u;  // RNE bf16
    Bh[t] = (unsigned short)(hb >> 16);
    Bl[t] = (unsigned short)bf16rne(wv - __uint_as_float(hb));
  }
  __syncthreads();
  if (c < 64) {
    double w[6];
#pragma unroll
    for (int d = 0; d < 6; d++) w[d] = (double)W1a[d * 64 + c];
    double b = (double)b1a[c];
    const double invN = 1.0 / (double)((size_t)NPTS * NK);
    double m1 = 0.0;
#pragma unroll
    for (int d = 0; d < 6; d++) m1 += w[d] * S[d];
    m1 *= invN;
    double q = 0.0;
#pragma unroll
    for (int a = 0; a < 6; a++)
#pragma unroll
      for (int d = 0; d < 6; d++) q += w[a] * w[d] * S[6 + a * 6 + d];
    q *= invN;
    double mu = m1 + b;
    double eh2 = q + 2.0 * b * m1 + b * b;
    double var = eh2 - mu * mu;
    if (var < 0.0) var = 0.0;
    double inv = 1.0 / sqrt(var + 1e-5);
    double sc = (double)g1[c] * inv;
    ss[c] = (float)sc;
    ss[64 + c] = (float)((double)be1[c] - mu * sc);
  }
}

// ---------------------------------------------------------------------------
// EdgeConv1 fused — MFMA (verified R12: absmax 1.95e-3).
// ---------------------------------------------------------------------------
#define EC1P 8
__global__ __launch_bounds__(256) void kec1(const float* __restrict__ pos,
                                            const int* __restrict__ idx,
                                            const float* __restrict__ ss,
                                            const float* __restrict__ W1a,
                                            const float* __restrict__ b1a,
                                            const unsigned short* __restrict__ Bh,
                                            const unsigned short* __restrict__ Bl,
                                            const float* __restrict__ b1b,
                                            float* __restrict__ x1) {
  __shared__ __align__(16) unsigned short Ah[4][3072];
  __shared__ __align__(16) unsigned short Al[4][3072];
  __shared__ float nbr[4][160];
  const int tid = threadIdx.x;
  const int lane = tid & 63;
  const int w = tid >> 6;
  const int p0 = blockIdx.x * EC1P + w * 2;  // this wave's 2 points

  unsigned short* ah = Ah[w];
  unsigned short* al = Al[w];
  float* nb = nbr[w];

  if (lane < 40) {
    const int j = idx[(size_t)p0 * NK + lane];
    nb[lane * 4 + 0] = pos[j * 3 + 0];
    nb[lane * 4 + 1] = pos[j * 3 + 1];
    nb[lane * 4 + 2] = pos[j * 3 + 2];
  }

  float wdf[3], wbt[3];
#pragma unroll
  for (int d = 0; d < 3; d++) {
    const float top = W1a[d * 64 + lane];
    const float bot = W1a[(3 + d) * 64 + lane];
    wdf[d] = top - bot;
    wbt[d] = bot;
  }
  const float b1 = b1a[lane];
  const float sc = ss[lane];
  const float sh = ss[64 + lane];
  const int lanepart = ((lane >> 5) * 512) + (((lane & 31) >> 3) * 128) + (lane & 7);
  __builtin_amdgcn_wave_barrier();

#pragma unroll
  for (int pp = 0; pp < 2; pp++) {
    const int p = p0 + pp;
    const float xi0 = pos[p * 3], xi1 = pos[p * 3 + 1], xi2 = pos[p * 3 + 2];
    const float pu = fmaf(xi2, wdf[2], fmaf(xi1, wdf[1], fmaf(xi0, wdf[0], b1)));
    for (int k = 0; k < NK; k++) {
      const int row = pp * NK + k;
      const float4 nbv = *(const float4*)&nb[row * 4];  // broadcast
      const float pv = fmaf(nbv.z, wbt[2], fmaf(nbv.y, wbt[1], nbv.x * wbt[0]));
      const float z = fmaxf(fmaf(pu + pv, sc, sh), 0.f);
      const unsigned u = __float_as_uint(z);
      const unsigned hb = (u + 0x7fffu + ((u >> 16) & 1u)) & 0xffff0000u;
      const int off = (row >> 4) * 1024 + (row & 15) * 8 + lanepart;
      ah[off] = (unsigned short)(hb >> 16);
      al[off] = (unsigned short)bf16rne(z - __uint_as_float(hb));
    }
  }
  __builtin_amdgcn_wave_barrier();

  bf16x8 bh[4][2], bl[4][2];
#pragma unroll
  for (int nt = 0; nt < 4; nt++)
#pragma unroll
    for (int ks = 0; ks < 2; ks++) {
      const int base = ((nt * 2 + ks) * 64 + lane) * 8;
      bh[nt][ks] = *(const bf16x8*)&Bh[base];
      bl[nt][ks] = *(const bf16x8*)&Bl[base];
    }

  float pA[4], pB[4];
#pragma unroll
  for (int nt = 0; nt < 4; nt++) {
    pA[nt] = -FLT_MAX;
    pB[nt] = -FLT_MAX;
  }
  const int q4 = (lane >> 4) * 4;

#pragma unroll
  for (int mt = 0; mt < 3; mt++) {
    const bf16x8 a_h0 = *(const bf16x8*)&ah[mt * 1024 + lane * 8];
    const bf16x8 a_l0 = *(const bf16x8*)&al[mt * 1024 + lane * 8];
    const bf16x8 a_h1 = *(const bf16x8*)&ah[mt * 1024 + 512 + lane * 8];
    const bf16x8 a_l1 = *(const bf16x8*)&al[mt * 1024 + 512 + lane * 8];
#pragma unroll
    for (int nt = 0; nt < 4; nt++) {
      f32x4 C = {0.f, 0.f, 0.f, 0.f};
      C = __builtin_amdgcn_mfma_f32_16x16x32_bf16(a_h0, bh[nt][0], C, 0, 0, 0);
      C = __builtin_amdgcn_mfma_f32_16x16x32_bf16(a_h0, bl[nt][0], C, 0, 0, 0);
      C = __builtin_amdgcn_mfma_f32_16x16x32_bf16(a_l0, bh[nt][0], C, 0, 0, 0);
      C = __builtin_amdgcn_mfma_f32_16x16x32_bf16(a_h1, bh[nt][1], C, 0, 0, 0);
      C = __builtin_amdgcn_mfma_f32_16x16x32_bf16(a_h1, bl[nt][1], C, 0, 0, 0);
      C = __builtin_amdgcn_mfma_f32_16x16x32_bf16(a_l1, bh[nt][1], C, 0, 0, 0);
#pragma unroll
      for (int r = 0; r < 4; r++) {
        const int row = mt * 16 + q4 + r;
        const float vv = C[r];
        if (row < NK) pA[nt] = fmaxf(pA[nt], vv);
        if (row >= NK && row < 2 * NK) pB[nt] = fmaxf(pB[nt], vv);
      }
    }
  }
#pragma unroll
  for (int s = 16; s < 64; s <<= 1) {
#pragma unroll
    for (int nt = 0; nt < 4; nt++) {
      pA[nt] = fmaxf(pA[nt], __shfl_xor(pA[nt], s, 64));
      pB[nt] = fmaxf(pB[nt], __shfl_xor(pB[nt], s, 64));
    }
  }
  if (lane < 16) {
#pragma unroll
    for (int nt = 0; nt < 4; nt++) {
      const float bb = b1b[nt * 16 + lane];
      x1[(size_t)p0 * 64 + nt * 16 + lane] = pA[nt] + bb;
      x1[(size_t)(p0 + 1) * 64 + nt * 16 + lane] = pB[nt] + bb;
    }
  }
}

// v[j,c] = x1_j . W2[64+d][c]
__global__ __launch_bounds__(256) void kv(const float* __restrict__ x1,
                                          const float* __restrict__ W2,
                                          float* __restrict__ v) {
  const int c = threadIdx.x & 127;
  const int sub = threadIdx.x >> 7;
  float wv[64];
#pragma unroll
  for (int d = 0; d < 64; d++) wv[d] = W2[(64 + d) * 128 + c];
  const int pbase = blockIdx.x * 64 + sub * 32;
  for (int i = 0; i < 32; i++) {
    const int p = pbase + i;
    const float4* xr = (const float4*)(x1 + (size_t)p * 64);
    float a0 = 0.f, a1 = 0.f;
#pragma unroll
    for (int dq = 0; dq < 16; dq++) {
      float4 xv = xr[dq];
      a0 = fmaf(xv.x, wv[dq * 4 + 0], a0);
      a1 = fmaf(xv.y, wv[dq * 4 + 1], a1);
      a0 = fmaf(xv.z, wv[dq * 4 + 2], a0);
      a1 = fmaf(xv.w, wv[dq * 4 + 3], a1);
    }
    v[(size_t)p * 128 + c] = a0 + a1;
  }
}

// Bc (192x128) and const bias cb (128)
__global__ __launch_bounds__(256) void kprep(const float* __restrict__ W2,
                                             const float* __restrict__ Wl,
                                             const float* __restrict__ b2,
                                             const float* __restrict__ bl,
                                             float* __restrict__ Bc,
                                             float* __restrict__ cb) {
  const int t = blockIdx.x * 256 + threadIdx.x;  // 8192
  const int d = t >> 7, c = t & 127;
  float s = Wl[d * 128 + c];
  for (int e = 0; e < 128; e++)
    s = fmaf(W2[d * 128 + e] - W2[(64 + d) * 128 + e], Wl[(64 + e) * 128 + c], s);
  Bc[d * 128 + c] = s;
  Bc[(64 + 2 * d) * 128 + c] = Wl[(64 + 2 * d) * 128 + c];
  Bc[(64 + 2 * d + 1) * 128 + c] = Wl[(64 + 2 * d + 1) * 128 + c];
  if (d == 0) {
    float sb = bl[c];
    for (int e = 0; e < 128; e++) sb = fmaf(b2[e], Wl[(64 + e) * 128 + c], sb);
    cb[c] = sb;
  }
}

// Final fused: AT = [x1^T ; maxgather(v)^T], GEMM with Bc, per-tile max.
// XCD swizzle: cloud = blockIdx & 31 (R13-verified).
#define ATS 72
#define BSS 132
__global__ __launch_bounds__(256) void kgemm(const float* __restrict__ x1,
                                             const float* __restrict__ v,
                                             const int* __restrict__ idx,
                                             const float* __restrict__ Bc,
                                             float* __restrict__ partial) {
  __shared__ float AT[192 * ATS];
  __shared__ float BS[16 * BSS];
  int* idxs = (int*)BS;
  const int tid = threadIdx.x;
  const int cloud = blockIdx.x & 31;  // XCD-local cloud assignment
  const int mb = blockIdx.x >> 5;
  const int pbase = cloud * 1024 + mb * 64;

#pragma unroll
  for (int r = 0; r < 5; r++) {
    int id = r * 256 + tid;
    idxs[id] = idx[(size_t)pbase * NK + id];
  }
#pragma unroll
  for (int r = 0; r < 16; r++) {
    int id = r * 256 + tid;
    int m = id >> 6, k = id & 63;
    AT[k * ATS + m] = x1[(size_t)(pbase + m) * 64 + k];
  }
  __syncthreads();
#pragma unroll
  for (int r = 0; r < 32; r++) {
    int id = r * 256 + tid;
    int m = id >> 7, kk = id & 127;
    const int* ip = &idxs[m * NK];
    float mx = -FLT_MAX;
#pragma unroll
    for (int k = 0; k < NK; k++) mx = fmaxf(mx, v[(size_t)ip[k] * 128 + kk]);
    AT[(64 + kk) * ATS + m] = mx;
  }
  __syncthreads();

  const int tr = tid >> 4, tc = tid & 15;
  float acc[4][8];
#pragma unroll
  for (int i = 0; i < 4; i++)
#pragma unroll
    for (int n = 0; n < 8; n++) acc[i][n] = 0.f;
  for (int kc = 0; kc < 12; kc++) {
#pragma unroll
    for (int r = 0; r < 8; r++) {
      int id = r * 256 + tid;
      int row = id >> 7, col = id & 127;
      BS[row * BSS + col] = Bc[(size_t)(kc * 16 + row) * 128 + col];
    }
    __syncthreads();
#pragma unroll
    for (int k = 0; k < 16; k++) {
      int kg = kc * 16 + k;
      float4 a = *(const float4*)&AT[kg * ATS + tr * 4];
      float4 b0 = *(const float4*)&BS[k * BSS + tc * 8];
      float4 b1 = *(const float4*)&BS[k * BSS + tc * 8 + 4];
      float av[4] = {a.x, a.y, a.z, a.w};
      float bv[8] = {b0.x, b0.y, b0.z, b0.w, b1.x, b1.y, b1.z, b1.w};
#pragma unroll
      for (int i = 0; i < 4; i++)
#pragma unroll
        for (int n = 0; n < 8; n++) acc[i][n] = fmaf(av[i], bv[n], acc[i][n]);
    }
    __syncthreads();
  }
#pragma unroll
  for (int n = 0; n < 8; n++) {
    float m4 = fmaxf(fmaxf(acc[0][n], acc[1][n]), fmaxf(acc[2][n], acc[3][n]));
    BS[tr * BSS + tc * 8 + n] = m4;
  }
  __syncthreads();
  if (tid < 128) {
    float m = -FLT_MAX;
#pragma unroll
    for (int rr = 0; rr < 16; rr++) m = fmaxf(m, BS[rr * BSS + tid]);
    partial[(size_t)(cloud * 16 + mb) * 128 + tid] = m;
  }
}

__global__ __launch_bounds__(256) void kred(const float* __restrict__ partial,
                                            const float* __restrict__ cb,
                                            float* __restrict__ out) {
  int t = blockIdx.x * 256 + threadIdx.x;  // 4096
  int b = t >> 7, c = t & 127;
  float m = -FLT_MAX;
#pragma unroll
  for (int mb = 0; mb < 16; mb++) m = fmaxf(m, partial[(size_t)(b * 16 + mb) * 128 + c]);
  out[t] = m + cb[c];
}

// ---------------------------------------------------------------------------
extern "C" void kernel_launch(void* const* d_in, const int* in_sizes, int n_in,
                              void* d_out, int out_size, void* d_ws, size_t ws_size,
                              hipStream_t stream) {
  const float* pos = (const float*)d_in[0];
  const float* W1a = (const float*)d_in[1];
  const float* b1a = (const float*)d_in[2];
  const float* g1 = (const float*)d_in[3];
  const float* be1 = (const float*)d_in[4];
  const float* W1b = (const float*)d_in[5];
  const float* b1b = (const float*)d_in[6];
  const float* W2 = (const float*)d_in[7];
  const float* b2 = (const float*)d_in[8];
  const float* Wl = (const float*)d_in[9];
  const float* bl = (const float*)d_in[10];
  float* out = (float*)d_out;

  // Workspace (floats): 9,181,952 = 36.7 MB (no D matrix anymore).
  float* ws = (float*)d_ws;
  float* x1 = ws;                                         // 2,097,152
  float* v = ws + 2097152;                                // 4,194,304
  int* idx = (int*)(ws + 6291456);                        // 655,360
  float* d2b = ws + 6946816;                              // 32,768
  double* Spart = (double*)(ws + 6979584);                // 10,752
  float* Bc = ws + 6990336;                               // 24,576
  float* cb = ws + 7014912;                               // 128
  float* ss = ws + 7015040;                               // 128
  unsigned short* Bh = (unsigned short*)(ws + 7015168);   // 2048 fl
  unsigned short* Bl = (unsigned short*)(ws + 7017216);   // 2048 fl
  float* partial = ws + 7019264;                          // 65,536
  unsigned short* Xfh = (unsigned short*)(ws + 7084800);  // 1,048,576 fl
  unsigned short* Xfl = (unsigned short*)(ws + 8133376);  // 1,048,576 fl
  const size_t base = 9181952;

  if (ws_size < base * sizeof(float)) return;  // fail soft

  // --- layer 1: kNN on pos (3D), fused dist+select ---
  kd2<<<128, 256, 0, stream>>>(pos, 3, d2b);
  kdsel3<<<2048, 256, 0, stream>>>(pos, d2b, idx);

  // --- EdgeConv1 (analytic BN + MFMA edge-GEMM) ---
  kstats<<<128, 256, 0, stream>>>(pos, idx, Spart);
  kbn<<<1, 256, 0, stream>>>(Spart, W1a, b1a, g1, be1, W1b, ss, Bh, Bl);
  kec1<<<NPTS / EC1P, 256, 0, stream>>>(pos, idx, ss, W1a, b1a, Bh, Bl, b1b, x1);

  // --- layer 2: kNN on x1 (64D), fused MFMA dist+select ---
  kd2<<<128, 256, 0, stream>>>(x1, 64, d2b);
  kxprep<<<1024, 256, 0, stream>>>(x1, Xfh, Xfl);
  kdsel64<<<2048, 256, 0, stream>>>(Xfh, Xfl, d2b, idx);

  // --- EdgeConv2 factored + fused final linear + pool ---
  kv<<<512, 256, 0, stream>>>(x1, W2, v);
  kprep<<<32, 256, 0, stream>>>(W2, Wl, b2, bl, Bc, cb);
  kgemm<<<512, 256, 0, stream>>>(x1, v, idx, Bc, partial);
  kred<<<16, 256, 0, stream>>>(partial, cb, out);
}

// Round 16
// 368.557 us; speedup vs baseline: 1.1028x; 1.1028x over previous
//
#include <hip/hip_runtime.h>
#include <cfloat>
#include <cstdint>

#define NB 32
#define NP 1024
#define NK 20
#define NPTS 32768  // NB*NP

typedef __attribute__((ext_vector_type(8))) short bf16x8;
typedef __attribute__((ext_vector_type(4))) float f32x4;

__device__ __forceinline__ unsigned bf16rne(float v) {
  const unsigned u = __float_as_uint(v);
  return (u + 0x7fffu + ((u >> 16) & 1u)) >> 16;
}

// ---------------------------------------------------------------------------
// d2[p] = sum x^2 (fp32 exact).
// ---------------------------------------------------------------------------
__global__ __launch_bounds__(256) void kd2(const float* __restrict__ x, int dim,
                                           float* __restrict__ d2) {
  int p = blockIdx.x * 256 + threadIdx.x;
  if (p >= NPTS) return;
  if (dim == 64) {
    const float4* xr = (const float4*)(x + (size_t)p * 64);
    float s = 0.f;
#pragma unroll
    for (int dq = 0; dq < 16; dq++) {
      float4 v = xr[dq];
      s = fmaf(v.x, v.x, s);
      s = fmaf(v.y, v.y, s);
      s = fmaf(v.z, v.z, s);
      s = fmaf(v.w, v.w, s);
    }
    d2[p] = s;
  } else {
    float s = 0.f;
#pragma unroll
    for (int d = 0; d < 3; d++) {
      float v = x[p * 3 + d];
      s = fmaf(v, v, s);
    }
    d2[p] = s;
  }
}

// ---------------------------------------------------------------------------
// kxprep: convert x1 into MFMA fragment order, bf16 hi/lo (HW-validated).
// Same array serves A and B operands of S = X X^T.
// ---------------------------------------------------------------------------
__global__ __launch_bounds__(256) void kxprep(const float* __restrict__ x,
                                              unsigned short* __restrict__ Xh,
                                              unsigned short* __restrict__ Xl) {
  const int t = blockIdx.x * 256 + threadIdx.x;  // 262144
  const int p = t >> 3, g = t & 7;               // k = g*8 + j
  const float4* xr = (const float4*)(x + (size_t)p * 64 + g * 8);
  const float4 v0 = xr[0];
  const float4 v1 = xr[1];
  const float vv[8] = {v0.x, v0.y, v0.z, v0.w, v1.x, v1.y, v1.z, v1.w};
  unsigned short h[8], l[8];
#pragma unroll
  for (int j = 0; j < 8; j++) {
    const float z = vv[j];
    const unsigned u = __float_as_uint(z);
    const unsigned hb = (u + 0x7fffu + ((u >> 16) & 1u)) & 0xffff0000u;
    h[j] = (unsigned short)(hb >> 16);
    l[j] = (unsigned short)bf16rne(z - __uint_as_float(hb));
  }
  const int off = (((p >> 4) * 2 + (g >> 2)) * 64 + ((g & 3) << 4) + (p & 15)) * 8;
  *(uint4*)&Xh[off] = *(const uint4*)&h[0];
  *(uint4*)&Xl[off] = *(const uint4*)&l[0];
}

// ---------------------------------------------------------------------------
// kdistm: MFMA distance matrix for dim=64 (bf16x3 split; R14-verified).
// ---------------------------------------------------------------------------
__global__ __launch_bounds__(256) void kdistm(const unsigned short* __restrict__ Xh,
                                              const unsigned short* __restrict__ Xl,
                                              const float* __restrict__ d2,
                                              int c0, int nc, float* __restrict__ D) {
  const int lane = threadIdx.x & 63;
  const int w = threadIdx.x >> 6;
  const int cloud = blockIdx.x % nc;  // XCD-local
  const int t = blockIdx.x / nc;
  const int tr0 = (t >> 3) * 128, tc0 = (t & 7) * 128;
  const int cb = (c0 + cloud) * 1024;
  const int rw = tr0 + w * 32;  // this wave's row base (local)

  bf16x8 Ah[2][2], Al[2][2];
#pragma unroll
  for (int mt = 0; mt < 2; mt++)
#pragma unroll
    for (int ks = 0; ks < 2; ks++) {
      const int tg = (cb + rw + mt * 16) >> 4;
      const size_t base = ((size_t)(tg * 2 + ks) * 64 + lane) * 8;
      Ah[mt][ks] = *(const bf16x8*)&Xh[base];
      Al[mt][ks] = *(const bf16x8*)&Xl[base];
    }
  float d2r[2][4];
#pragma unroll
  for (int mt = 0; mt < 2; mt++)
#pragma unroll
    for (int r = 0; r < 4; r++)
      d2r[mt][r] = d2[cb + rw + mt * 16 + (lane >> 4) * 4 + r];

  for (int nt = 0; nt < 8; nt++) {
    const int cg = cb + tc0 + nt * 16;
    bf16x8 Bh2[2], Bl2[2];
#pragma unroll
    for (int ks = 0; ks < 2; ks++) {
      const int tg = cg >> 4;
      const size_t base = ((size_t)(tg * 2 + ks) * 64 + lane) * 8;
      Bh2[ks] = *(const bf16x8*)&Xh[base];
      Bl2[ks] = *(const bf16x8*)&Xl[base];
    }
    const float d2c = d2[cg + (lane & 15)];
#pragma unroll
    for (int mt = 0; mt < 2; mt++) {
      f32x4 C = {0.f, 0.f, 0.f, 0.f};
      C = __builtin_amdgcn_mfma_f32_16x16x32_bf16(Ah[mt][0], Bh2[0], C, 0, 0, 0);
      C = __builtin_amdgcn_mfma_f32_16x16x32_bf16(Ah[mt][0], Bl2[0], C, 0, 0, 0);
      C = __builtin_amdgcn_mfma_f32_16x16x32_bf16(Al[mt][0], Bh2[0], C, 0, 0, 0);
      C = __builtin_amdgcn_mfma_f32_16x16x32_bf16(Ah[mt][1], Bh2[1], C, 0, 0, 0);
      C = __builtin_amdgcn_mfma_f32_16x16x32_bf16(Ah[mt][1], Bl2[1], C, 0, 0, 0);
      C = __builtin_amdgcn_mfma_f32_16x16x32_bf16(Al[mt][1], Bh2[1], C, 0, 0, 0);
#pragma unroll
      for (int r = 0; r < 4; r++) {
        const int row = cloud * 1024 + rw + mt * 16 + (lane >> 4) * 4 + r;
        const int col = tc0 + nt * 16 + (lane & 15);
        D[(size_t)row * 1024 + col] = fmaf(-2.f, C[r], d2r[mt][r] + d2c);
      }
    }
  }
}

// ---------------------------------------------------------------------------
// kdist: fp32 distance matrix (dim=3; trivial compute, write-bound).
// ---------------------------------------------------------------------------
template <int DIM>
__global__ __launch_bounds__(256) void kdist(const float* __restrict__ x,
                                             const float* __restrict__ d2,
                                             int c0, int nc, float* __restrict__ D) {
  constexpr int KC = (DIM == 64) ? 32 : 3;
  __shared__ float As[KC][132];
  __shared__ float Bs[KC][132];
  const int tid = threadIdx.x;
  const int cloud = blockIdx.x % nc;  // XCD-local
  const int t = blockIdx.x / nc;
  const int tr0 = (t >> 3) * 128, tc0 = (t & 7) * 128;
  const int cb = (c0 + cloud) * 1024;
  const int tr = tid >> 4, tc = tid & 15;

  float acc[8][8];
#pragma unroll
  for (int i = 0; i < 8; i++)
#pragma unroll
    for (int j = 0; j < 8; j++) acc[i][j] = 0.f;

  for (int kc = 0; kc < DIM; kc += KC) {
    __syncthreads();
    if constexpr (DIM == 64) {
      const int row = tid >> 1, seg = tid & 1;
      const float4* sa = (const float4*)(x + (size_t)(cb + tr0 + row) * 64 + kc + seg * 16);
      const float4* sb = (const float4*)(x + (size_t)(cb + tc0 + row) * 64 + kc + seg * 16);
#pragma unroll
      for (int i = 0; i < 4; i++) {
        float4 va = sa[i];
        float4 vb = sb[i];
        const int k0 = seg * 16 + i * 4;
        As[k0 + 0][row] = va.x;
        As[k0 + 1][row] = va.y;
        As[k0 + 2][row] = va.z;
        As[k0 + 3][row] = va.w;
        Bs[k0 + 0][row] = vb.x;
        Bs[k0 + 1][row] = vb.y;
        Bs[k0 + 2][row] = vb.z;
        Bs[k0 + 3][row] = vb.w;
      }
    } else {
      if (tid < 128) {
#pragma unroll
        for (int d = 0; d < 3; d++) {
          As[d][tid] = x[(size_t)(cb + tr0 + tid) * 3 + d];
          Bs[d][tid] = x[(size_t)(cb + tc0 + tid) * 3 + d];
        }
      }
    }
    __syncthreads();
#pragma unroll
    for (int k = 0; k < KC; k++) {
      float a[8], b[8];
      *(float4*)&a[0] = *(const float4*)&As[k][tr * 8];
      *(float4*)&a[4] = *(const float4*)&As[k][tr * 8 + 4];
      *(float4*)&b[0] = *(const float4*)&Bs[k][tc * 8];
      *(float4*)&b[4] = *(const float4*)&Bs[k][tc * 8 + 4];
#pragma unroll
      for (int i = 0; i < 8; i++)
#pragma unroll
        for (int j = 0; j < 8; j++) acc[i][j] = fmaf(a[i], b[j], acc[i][j]);
    }
  }
  float d2r[8], d2c[8];
#pragma unroll
  for (int i = 0; i < 8; i++) d2r[i] = d2[cb + tr0 + tr * 8 + i];
#pragma unroll
  for (int j = 0; j < 8; j++) d2c[j] = d2[cb + tc0 + tc * 8 + j];
#pragma unroll
  for (int i = 0; i < 8; i++) {
    float o[8];
#pragma unroll
    for (int j = 0; j < 8; j++) o[j] = fmaf(-2.f, acc[i][j], d2r[i] + d2c[j]);
    float* dst = &D[(size_t)(cloud * 1024 + tr0 + tr * 8 + i) * 1024 + tc0 + tc * 8];
    *(float4*)&dst[0] = *(const float4*)&o[0];
    *(float4*)&dst[4] = *(const float4*)&o[4];
  }
}

// ---------------------------------------------------------------------------
// kselect v3: exact top-20. Binary search runs on 32-BIT sortable distances
// (u64 compares are multi-op on gfx950; u32 are single). Superset proof: if
// cnt{u<m2} in [20,63], every true top-20 element has u<m2 (else >=20
// strictly-closer elements beat it). The u64 rank pass (index tie-break)
// then extracts the exact ordered top-20. Tie-plateau (no 32-bit pivot)
// falls back to the R4-validated full u64 search — rare, wave-uniform.
// ---------------------------------------------------------------------------
__global__ __launch_bounds__(256) void kselect(const float* __restrict__ D,
                                               int c0, int* __restrict__ idxo) {
  __shared__ unsigned long long lw[4][64];
  const int lane = threadIdx.x & 63;
  const int sub = threadIdx.x >> 6;
  const int pchunk = blockIdx.x * 4 + sub;  // point within chunk
  const int pg = c0 * 1024 + pchunk;        // global point
  const int gbase = (pg >> 10) << 10;       // cloud base (global)

  unsigned k32[16];
  const float4* dr = (const float4*)(D + (size_t)pchunk * 1024 + lane * 4);
#pragma unroll
  for (int i = 0; i < 4; i++) {
    const float4 d4 = dr[i * 64];  // q = i*256 + lane*4 ..+3
    const float dv[4] = {d4.x, d4.y, d4.z, d4.w};
#pragma unroll
    for (int j = 0; j < 4; j++) {
      unsigned u = __float_as_uint(dv[j]);
      u ^= (((int)u >> 31) | 0x80000000u);  // sortable transform
      k32[i * 4 + j] = u;
    }
  }

  // 32-bit min/max butterfly seed
  unsigned mn = k32[0], mx = k32[0];
#pragma unroll
  for (int i = 1; i < 16; i++) {
    mn = k32[i] < mn ? k32[i] : mn;
    mx = k32[i] > mx ? k32[i] : mx;
  }
#pragma unroll
  for (int s = 1; s < 64; s <<= 1) {
    const unsigned a = __shfl_xor(mn, s, 64);
    const unsigned b = __shfl_xor(mx, s, 64);
    mn = a < mn ? a : mn;
    mx = b > mx ? b : mx;
  }

  unsigned long long midk = 0;
  bool found = false;
  {
    unsigned long long lo = mn, hi = (unsigned long long)mx + 1;
    for (int it = 0; it < 33 && !found; ++it) {
      if (hi - lo <= 1) break;  // plateau straddles [20,63] -> fallback
      const unsigned long long m2 = lo + ((hi - lo) >> 1);
      const unsigned m32 = (unsigned)m2;  // m2 < hi <= 2^32 -> fits
      int cnt = 0;
#pragma unroll
      for (int i = 0; i < 16; i++) cnt += (k32[i] < m32) ? 1 : 0;
#pragma unroll
      for (int s = 1; s < 64; s <<= 1) cnt += __shfl_xor(cnt, s, 64);
      if (cnt < 20)
        lo = m2;
      else if (cnt > 63)
        hi = m2;
      else {
        midk = (m2 << 10);
        found = true;
      }
    }
  }
  if (!found) {
    // exact u64 fallback (keys distinct -> window guaranteed)
    unsigned long long key[16];
#pragma unroll
    for (int i = 0; i < 4; i++)
#pragma unroll
      for (int j = 0; j < 4; j++)
        key[i * 4 + j] = ((unsigned long long)k32[i * 4 + j] << 10) |
                         (unsigned)(i * 256 + lane * 4 + j);
    unsigned long long mn64 = key[0], mx64 = key[0];
#pragma unroll
    for (int i = 1; i < 16; i++) {
      mn64 = key[i] < mn64 ? key[i] : mn64;
      mx64 = key[i] > mx64 ? key[i] : mx64;
    }
#pragma unroll
    for (int s = 1; s < 64; s <<= 1) {
      const unsigned long long a = __shfl_xor(mn64, s, 64);
      const unsigned long long b = __shfl_xor(mx64, s, 64);
      mn64 = a < mn64 ? a : mn64;
      mx64 = b > mx64 ? b : mx64;
    }
    unsigned long long lo = mn64, hi = mx64 + 1;
    bool f2 = false;
    for (int it = 0; it < 48 && !f2; ++it) {
      const unsigned long long m2 = lo + ((hi - lo) >> 1);
      int cnt = 0;
#pragma unroll
      for (int i = 0; i < 16; i++) cnt += (key[i] < m2) ? 1 : 0;
#pragma unroll
      for (int s = 1; s < 64; s <<= 1) cnt += __shfl_xor(cnt, s, 64);
      if (cnt < 20)
        lo = m2;
      else if (cnt > 63)
        hi = m2;
      else {
        midk = m2;
        f2 = true;
      }
    }
  }

  // compaction on u64 keys against midk, then fixed-64 rank pass
  unsigned mask = 0;
  unsigned long long key64[16];
#pragma unroll
  for (int i = 0; i < 4; i++)
#pragma unroll
    for (int j = 0; j < 4; j++) {
      const int ii = i * 4 + j;
      key64[ii] = ((unsigned long long)k32[ii] << 10) |
                  (unsigned)(i * 256 + lane * 4 + j);
      mask |= (key64[ii] < midk) ? (1u << ii) : 0u;
    }
  const int lc = __popc(mask);
  int x = lc;
#pragma unroll
  for (int s = 1; s < 64; s <<= 1) {
    const int y = __shfl_up(x, s, 64);
    if (lane >= s) x += y;
  }
  int off = x - lc;  // exclusive prefix
  unsigned long long* w = lw[sub];
  w[lane] = ~0ULL;  // pad for fixed-64 rank pass
  __builtin_amdgcn_wave_barrier();
#pragma unroll
  for (int i = 0; i < 16; i++) {
    if ((mask & (1u << i)) && off < 64) {
      w[off] = key64[i];
      off++;
    }
  }
  __builtin_amdgcn_wave_barrier();
  const unsigned long long K = w[lane];
  int rank = 0;
#pragma unroll
  for (int m = 0; m < 64; m++) rank += (K > w[m]) ? 1 : 0;
  if (K != ~0ULL && rank < NK)
    idxo[(size_t)pg * NK + rank] = gbase + (int)(K & 1023u);
}

// ---------------------------------------------------------------------------
// Edge moments, atomic-free.
// ---------------------------------------------------------------------------
__global__ __launch_bounds__(256) void kstats(const float* __restrict__ pos,
                                              const int* __restrict__ idx,
                                              double* __restrict__ Spart) {
  __shared__ float red[4][42];
  const int tid = threadIdx.x;
  const int w = tid >> 6;
  int p = blockIdx.x * 256 + tid;
  float xi0 = pos[p * 3], xi1 = pos[p * 3 + 1], xi2 = pos[p * 3 + 2];
  float s1[6];
  float s2[36];
#pragma unroll
  for (int a = 0; a < 6; a++) s1[a] = 0.f;
#pragma unroll
  for (int a = 0; a < 36; a++) s2[a] = 0.f;
  for (int k = 0; k < NK; k++) {
    int j = idx[p * NK + k];
    float e[6];
    e[0] = xi0;
    e[1] = xi1;
    e[2] = xi2;
    e[3] = pos[j * 3] - xi0;
    e[4] = pos[j * 3 + 1] - xi1;
    e[5] = pos[j * 3 + 2] - xi2;
#pragma unroll
    for (int a = 0; a < 6; a++) {
      s1[a] += e[a];
#pragma unroll
      for (int b = 0; b < 6; b++) s2[a * 6 + b] = fmaf(e[a], e[b], s2[a * 6 + b]);
    }
  }
#pragma unroll
  for (int a = 0; a < 6; a++) {
#pragma unroll
    for (int m = 1; m < 64; m <<= 1) s1[a] += __shfl_xor(s1[a], m, 64);
  }
#pragma unroll
  for (int a = 0; a < 36; a++) {
#pragma unroll
    for (int m = 1; m < 64; m <<= 1) s2[a] += __shfl_xor(s2[a], m, 64);
  }
  if ((tid & 63) == 0) {
#pragma unroll
    for (int a = 0; a < 6; a++) red[w][a] = s1[a];
#pragma unroll
    for (int a = 0; a < 36; a++) red[w][6 + a] = s2[a];
  }
  __syncthreads();
  if (tid < 42) {
    double t = (double)red[0][tid] + (double)red[1][tid] + (double)red[2][tid] +
               (double)red[3][tid];
    Spart[(size_t)blockIdx.x * 42 + tid] = t;
  }
}

// ---------------------------------------------------------------------------
// kbn: stats reduce -> BN scale/shift; W1b pre-swizzle to B-frag bf16 hi/lo.
// ---------------------------------------------------------------------------
__global__ void kbn(const double* __restrict__ Spart, const float* __restrict__ W1a,
                    const float* __restrict__ b1a, const float* __restrict__ g1,
                    const float* __restrict__ be1, const float* __restrict__ W1b,
                    float* __restrict__ ss, unsigned short* __restrict__ Bh,
                    unsigned short* __restrict__ Bl) {
  __shared__ double S[42];
  const int c = threadIdx.x;  // 256 threads
  if (c < 42) {
    double t = 0.0;
    for (int b = 0; b < 128; b++) t += Spart[(size_t)b * 42 + c];
    S[c] = t;
  }
  for (int t = c; t < 4096; t += 256) {
    const int j = t & 7, L = (t >> 3) & 63, f = t >> 9;  // f = nt*2+ks
    const int nt = f >> 1, ks = f & 1;
    const int k = ks * 32 + (L >> 4) * 8 + j;
    const int n = nt * 16 + (L & 15);
    const float wv = W1b[k * 64 + n];
    const unsigned u = __float_as_uint(wv);
    const unsigned hb = (u + 0x7fffu + ((u >> 16) & 1u)) & 0xffff0000u;  // RNE bf16
    Bh[t] = (unsigned short)(hb >> 16);
    Bl[t] = (unsigned short)bf16rne(wv - __uint_as_float(hb));
  }
  __syncthreads();
  if (c < 64) {
    double w[6];
#pragma unroll
    for (int d = 0; d < 6; d++) w[d] = (double)W1a[d * 64 + c];
    double b = (double)b1a[c];
    const double invN = 1.0 / (double)((size_t)NPTS * NK);
    double m1 = 0.0;
#pragma unroll
    for (int d = 0; d < 6; d++) m1 += w[d] * S[d];
    m1 *= invN;
    double q = 0.0;
#pragma unroll
    for (int a = 0; a < 6; a++)
#pragma unroll
      for (int d = 0; d < 6; d++) q += w[a] * w[d] * S[6 + a * 6 + d];
    q *= invN;
    double mu = m1 + b;
    double eh2 = q + 2.0 * b * m1 + b * b;
    double var = eh2 - mu * mu;
    if (var < 0.0) var = 0.0;
    double inv = 1.0 / sqrt(var + 1e-5);
    double sc = (double)g1[c] * inv;
    ss[c] = (float)sc;
    ss[64 + c] = (float)((double)be1[c] - mu * sc);
  }
}

// ---------------------------------------------------------------------------
// EdgeConv1 fused — MFMA (verified R12: absmax 1.95e-3).
// ---------------------------------------------------------------------------
#define EC1P 8
__global__ __launch_bounds__(256) void kec1(const float* __restrict__ pos,
                                            const int* __restrict__ idx,
                                            const float* __restrict__ ss,
                                            const float* __restrict__ W1a,
                                            const float* __restrict__ b1a,
                                            const unsigned short* __restrict__ Bh,
                                            const unsigned short* __restrict__ Bl,
                                            const float* __restrict__ b1b,
                                            float* __restrict__ x1) {
  __shared__ __align__(16) unsigned short Ah[4][3072];
  __shared__ __align__(16) unsigned short Al[4][3072];
  __shared__ float nbr[4][160];
  const int tid = threadIdx.x;
  const int lane = tid & 63;
  const int w = tid >> 6;
  const int p0 = blockIdx.x * EC1P + w * 2;  // this wave's 2 points

  unsigned short* ah = Ah[w];
  unsigned short* al = Al[w];
  float* nb = nbr[w];

  if (lane < 40) {
    const int j = idx[(size_t)p0 * NK + lane];
    nb[lane * 4 + 0] = pos[j * 3 + 0];
    nb[lane * 4 + 1] = pos[j * 3 + 1];
    nb[lane * 4 + 2] = pos[j * 3 + 2];
  }

  float wdf[3], wbt[3];
#pragma unroll
  for (int d = 0; d < 3; d++) {
    const float top = W1a[d * 64 + lane];
    const float bot = W1a[(3 + d) * 64 + lane];
    wdf[d] = top - bot;
    wbt[d] = bot;
  }
  const float b1 = b1a[lane];
  const float sc = ss[lane];
  const float sh = ss[64 + lane];
  const int lanepart = ((lane >> 5) * 512) + (((lane & 31) >> 3) * 128) + (lane & 7);
  __builtin_amdgcn_wave_barrier();

#pragma unroll
  for (int pp = 0; pp < 2; pp++) {
    const int p = p0 + pp;
    const float xi0 = pos[p * 3], xi1 = pos[p * 3 + 1], xi2 = pos[p * 3 + 2];
    const float pu = fmaf(xi2, wdf[2], fmaf(xi1, wdf[1], fmaf(xi0, wdf[0], b1)));
    for (int k = 0; k < NK; k++) {
      const int row = pp * NK + k;
      const float4 nbv = *(const float4*)&nb[row * 4];  // broadcast
      const float pv = fmaf(nbv.z, wbt[2], fmaf(nbv.y, wbt[1], nbv.x * wbt[0]));
      const float z = fmaxf(fmaf(pu + pv, sc, sh), 0.f);
      const unsigned u = __float_as_uint(z);
      const unsigned hb = (u + 0x7fffu + ((u >> 16) & 1u)) & 0xffff0000u;
      const int off = (row >> 4) * 1024 + (row & 15) * 8 + lanepart;
      ah[off] = (unsigned short)(hb >> 16);
      al[off] = (unsigned short)bf16rne(z - __uint_as_float(hb));
    }
  }
  __builtin_amdgcn_wave_barrier();

  bf16x8 bh[4][2], bl[4][2];
#pragma unroll
  for (int nt = 0; nt < 4; nt++)
#pragma unroll
    for (int ks = 0; ks < 2; ks++) {
      const int base = ((nt * 2 + ks) * 64 + lane) * 8;
      bh[nt][ks] = *(const bf16x8*)&Bh[base];
      bl[nt][ks] = *(const bf16x8*)&Bl[base];
    }

  float pA[4], pB[4];
#pragma unroll
  for (int nt = 0; nt < 4; nt++) {
    pA[nt] = -FLT_MAX;
    pB[nt] = -FLT_MAX;
  }
  const int q4 = (lane >> 4) * 4;

#pragma unroll
  for (int mt = 0; mt < 3; mt++) {
    const bf16x8 a_h0 = *(const bf16x8*)&ah[mt * 1024 + lane * 8];
    const bf16x8 a_l0 = *(const bf16x8*)&al[mt * 1024 + lane * 8];
    const bf16x8 a_h1 = *(const bf16x8*)&ah[mt * 1024 + 512 + lane * 8];
    const bf16x8 a_l1 = *(const bf16x8*)&al[mt * 1024 + 512 + lane * 8];
#pragma unroll
    for (int nt = 0; nt < 4; nt++) {
      f32x4 C = {0.f, 0.f, 0.f, 0.f};
      C = __builtin_amdgcn_mfma_f32_16x16x32_bf16(a_h0, bh[nt][0], C, 0, 0, 0);
      C = __builtin_amdgcn_mfma_f32_16x16x32_bf16(a_h0, bl[nt][0], C, 0, 0, 0);
      C = __builtin_amdgcn_mfma_f32_16x16x32_bf16(a_l0, bh[nt][0], C, 0, 0, 0);
      C = __builtin_amdgcn_mfma_f32_16x16x32_bf16(a_h1, bh[nt][1], C, 0, 0, 0);
      C = __builtin_amdgcn_mfma_f32_16x16x32_bf16(a_h1, bl[nt][1], C, 0, 0, 0);
      C = __builtin_amdgcn_mfma_f32_16x16x32_bf16(a_l1, bh[nt][1], C, 0, 0, 0);
#pragma unroll
      for (int r = 0; r < 4; r++) {
        const int row = mt * 16 + q4 + r;
        const float vv = C[r];
        if (row < NK) pA[nt] = fmaxf(pA[nt], vv);
        if (row >= NK && row < 2 * NK) pB[nt] = fmaxf(pB[nt], vv);
      }
    }
  }
#pragma unroll
  for (int s = 16; s < 64; s <<= 1) {
#pragma unroll
    for (int nt = 0; nt < 4; nt++) {
      pA[nt] = fmaxf(pA[nt], __shfl_xor(pA[nt], s, 64));
      pB[nt] = fmaxf(pB[nt], __shfl_xor(pB[nt], s, 64));
    }
  }
  if (lane < 16) {
#pragma unroll
    for (int nt = 0; nt < 4; nt++) {
      const float bb = b1b[nt * 16 + lane];
      x1[(size_t)p0 * 64 + nt * 16 + lane] = pA[nt] + bb;
      x1[(size_t)(p0 + 1) * 64 + nt * 16 + lane] = pB[nt] + bb;
    }
  }
}

// v[j,c] = x1_j . W2[64+d][c]
__global__ __launch_bounds__(256) void kv(const float* __restrict__ x1,
                                          const float* __restrict__ W2,
                                          float* __restrict__ v) {
  const int c = threadIdx.x & 127;
  const int sub = threadIdx.x >> 7;
  float wv[64];
#pragma unroll
  for (int d = 0; d < 64; d++) wv[d] = W2[(64 + d) * 128 + c];
  const int pbase = blockIdx.x * 64 + sub * 32;
  for (int i = 0; i < 32; i++) {
    const int p = pbase + i;
    const float4* xr = (const float4*)(x1 + (size_t)p * 64);
    float a0 = 0.f, a1 = 0.f;
#pragma unroll
    for (int dq = 0; dq < 16; dq++) {
      float4 xv = xr[dq];
      a0 = fmaf(xv.x, wv[dq * 4 + 0], a0);
      a1 = fmaf(xv.y, wv[dq * 4 + 1], a1);
      a0 = fmaf(xv.z, wv[dq * 4 + 2], a0);
      a1 = fmaf(xv.w, wv[dq * 4 + 3], a1);
    }
    v[(size_t)p * 128 + c] = a0 + a1;
  }
}

// Bc (192x128) and const bias cb (128)
__global__ __launch_bounds__(256) void kprep(const float* __restrict__ W2,
                                             const float* __restrict__ Wl,
                                             const float* __restrict__ b2,
                                             const float* __restrict__ bl,
                                             float* __restrict__ Bc,
                                             float* __restrict__ cb) {
  const int t = blockIdx.x * 256 + threadIdx.x;  // 8192
  const int d = t >> 7, c = t & 127;
  float s = Wl[d * 128 + c];
  for (int e = 0; e < 128; e++)
    s = fmaf(W2[d * 128 + e] - W2[(64 + d) * 128 + e], Wl[(64 + e) * 128 + c], s);
  Bc[d * 128 + c] = s;
  Bc[(64 + 2 * d) * 128 + c] = Wl[(64 + 2 * d) * 128 + c];
  Bc[(64 + 2 * d + 1) * 128 + c] = Wl[(64 + 2 * d + 1) * 128 + c];
  if (d == 0) {
    float sb = bl[c];
    for (int e = 0; e < 128; e++) sb = fmaf(b2[e], Wl[(64 + e) * 128 + c], sb);
    cb[c] = sb;
  }
}

// Final fused: AT = [x1^T ; maxgather(v)^T], GEMM with Bc, per-tile max.
// XCD swizzle: cloud = blockIdx & 31 (R13-verified).
#define ATS 72
#define BSS 132
__global__ __launch_bounds__(256) void kgemm(const float* __restrict__ x1,
                                             const float* __restrict__ v,
                                             const int* __restrict__ idx,
                                             const float* __restrict__ Bc,
                                             float* __restrict__ partial) {
  __shared__ float AT[192 * ATS];
  __shared__ float BS[16 * BSS];
  int* idxs = (int*)BS;
  const int tid = threadIdx.x;
  const int cloud = blockIdx.x & 31;  // XCD-local cloud assignment
  const int mb = blockIdx.x >> 5;
  const int pbase = cloud * 1024 + mb * 64;

#pragma unroll
  for (int r = 0; r < 5; r++) {
    int id = r * 256 + tid;
    idxs[id] = idx[(size_t)pbase * NK + id];
  }
#pragma unroll
  for (int r = 0; r < 16; r++) {
    int id = r * 256 + tid;
    int m = id >> 6, k = id & 63;
    AT[k * ATS + m] = x1[(size_t)(pbase + m) * 64 + k];
  }
  __syncthreads();
#pragma unroll
  for (int r = 0; r < 32; r++) {
    int id = r * 256 + tid;
    int m = id >> 7, kk = id & 127;
    const int* ip = &idxs[m * NK];
    float mx = -FLT_MAX;
#pragma unroll
    for (int k = 0; k < NK; k++) mx = fmaxf(mx, v[(size_t)ip[k] * 128 + kk]);
    AT[(64 + kk) * ATS + m] = mx;
  }
  __syncthreads();

  const int tr = tid >> 4, tc = tid & 15;
  float acc[4][8];
#pragma unroll
  for (int i = 0; i < 4; i++)
#pragma unroll
    for (int n = 0; n < 8; n++) acc[i][n] = 0.f;
  for (int kc = 0; kc < 12; kc++) {
#pragma unroll
    for (int r = 0; r < 8; r++) {
      int id = r * 256 + tid;
      int row = id >> 7, col = id & 127;
      BS[row * BSS + col] = Bc[(size_t)(kc * 16 + row) * 128 + col];
    }
    __syncthreads();
#pragma unroll
    for (int k = 0; k < 16; k++) {
      int kg = kc * 16 + k;
      float4 a = *(const float4*)&AT[kg * ATS + tr * 4];
      float4 b0 = *(const float4*)&BS[k * BSS + tc * 8];
      float4 b1 = *(const float4*)&BS[k * BSS + tc * 8 + 4];
      float av[4] = {a.x, a.y, a.z, a.w};
      float bv[8] = {b0.x, b0.y, b0.z, b0.w, b1.x, b1.y, b1.z, b1.w};
#pragma unroll
      for (int i = 0; i < 4; i++)
#pragma unroll
        for (int n = 0; n < 8; n++) acc[i][n] = fmaf(av[i], bv[n], acc[i][n]);
    }
    __syncthreads();
  }
#pragma unroll
  for (int n = 0; n < 8; n++) {
    float m4 = fmaxf(fmaxf(acc[0][n], acc[1][n]), fmaxf(acc[2][n], acc[3][n]));
    BS[tr * BSS + tc * 8 + n] = m4;
  }
  __syncthreads();
  if (tid < 128) {
    float m = -FLT_MAX;
#pragma unroll
    for (int rr = 0; rr < 16; rr++) m = fmaxf(m, BS[rr * BSS + tid]);
    partial[(size_t)(cloud * 16 + mb) * 128 + tid] = m;
  }
}

__global__ __launch_bounds__(256) void kred(const float* __restrict__ partial,
                                            const float* __restrict__ cb,
                                            float* __restrict__ out) {
  int t = blockIdx.x * 256 + threadIdx.x;  // 4096
  int b = t >> 7, c = t & 127;
  float m = -FLT_MAX;
#pragma unroll
  for (int mb = 0; mb < 16; mb++) m = fmaxf(m, partial[(size_t)(b * 16 + mb) * 128 + c]);
  out[t] = m + cb[c];
}

// ---------------------------------------------------------------------------
extern "C" void kernel_launch(void* const* d_in, const int* in_sizes, int n_in,
                              void* d_out, int out_size, void* d_ws, size_t ws_size,
                              hipStream_t stream) {
  const float* pos = (const float*)d_in[0];
  const float* W1a = (const float*)d_in[1];
  const float* b1a = (const float*)d_in[2];
  const float* g1 = (const float*)d_in[3];
  const float* be1 = (const float*)d_in[4];
  const float* W1b = (const float*)d_in[5];
  const float* b1b = (const float*)d_in[6];
  const float* W2 = (const float*)d_in[7];
  const float* b2 = (const float*)d_in[8];
  const float* Wl = (const float*)d_in[9];
  const float* bl = (const float*)d_in[10];
  float* out = (float*)d_out;

  // Base workspace (floats). D-matrix chunk after it.
  float* ws = (float*)d_ws;
  float* x1 = ws;                                        // 2,097,152
  float* v = ws + 2097152;                               // 4,194,304
  int* idx = (int*)(ws + 6291456);                       // 655,360
  float* d2b = ws + 6946816;                             // 32,768
  double* Spart = (double*)(ws + 6979584);               // 10,752
  float* Bc = ws + 6990336;                              // 24,576
  float* cb = ws + 7014912;                              // 128
  float* ss = ws + 7015040;                              // 128
  unsigned short* Bh = (unsigned short*)(ws + 7015168);  // 2048 fl
  unsigned short* Bl = (unsigned short*)(ws + 7017216);  // 2048 fl
  float* partial = ws + 7019264;                         // 65,536
  unsigned short* Xfh = (unsigned short*)(ws + 7084800); // 1,048,576 fl
  unsigned short* Xfl = (unsigned short*)(ws + 8133376); // 1,048,576 fl
  const size_t base = 9181952;
  float* D = ws + base;

  if (ws_size < (base + 1024 * 1024) * sizeof(float)) return;  // fail soft

  // D chunk: largest power-of-2 cloud count that fits (<= 32).
  size_t avail = ws_size / sizeof(float) - base;
  int nc = 1;
  for (int c = 32; c >= 1; c >>= 1)
    if ((size_t)c * 1024 * 1024 <= avail) {
      nc = c;
      break;
    }

  // --- layer 1: kNN on pos (3D) ---
  kd2<<<128, 256, 0, stream>>>(pos, 3, d2b);
  for (int c0 = 0; c0 < NB; c0 += nc) {
    kdist<3><<<nc * 64, 256, 0, stream>>>(pos, d2b, c0, nc, D);
    kselect<<<nc * 256, 256, 0, stream>>>(D, c0, idx);
  }

  // --- EdgeConv1 (analytic BN + MFMA edge-GEMM) ---
  kstats<<<128, 256, 0, stream>>>(pos, idx, Spart);
  kbn<<<1, 256, 0, stream>>>(Spart, W1a, b1a, g1, be1, W1b, ss, Bh, Bl);
  kec1<<<NPTS / EC1P, 256, 0, stream>>>(pos, idx, ss, W1a, b1a, Bh, Bl, b1b, x1);

  // --- layer 2: kNN on x1 (64D) — MFMA distance matrix ---
  kd2<<<128, 256, 0, stream>>>(x1, 64, d2b);
  kxprep<<<1024, 256, 0, stream>>>(x1, Xfh, Xfl);
  for (int c0 = 0; c0 < NB; c0 += nc) {
    kdistm<<<nc * 64, 256, 0, stream>>>(Xfh, Xfl, d2b, c0, nc, D);
    kselect<<<nc * 256, 256, 0, stream>>>(D, c0, idx);
  }

  // --- EdgeConv2 factored + fused final linear + pool ---
  kv<<<512, 256, 0, stream>>>(x1, W2, v);
  kprep<<<32, 256, 0, stream>>>(W2, Wl, b2, bl, Bc, cb);
  kgemm<<<512, 256, 0, stream>>>(x1, v, idx, Bc, partial);
  kred<<<16, 256, 0, stream>>>(partial, cb, out);
}